// Round 25
// baseline (155.907 us; speedup 1.0000x reference)
//
#include <hip/hip_runtime.h>
#include <stdint.h>

// Cross-attention forward: B=2, N1=N2=2048, HID=768, 12 heads x 64.
// Round 24: compose proven halves — flash+merge from r23 (PASS; mask-C-init
// + deferred ones-B l-MFMA, hazard-safe), attnw from r21 (PASS, ~45us,
// VGPR ~48; r23's attnw mask-C-init blew VGPR to 140 -> Occ 11% -> 91us).
// prep/proj byte-identical throughout.

typedef __attribute__((ext_vector_type(8))) short bf16x8;
typedef __attribute__((ext_vector_type(4))) short bf16x4;
typedef __attribute__((ext_vector_type(4))) float f32x4;

constexpr int B_  = 2;
constexpr int N_  = 2048;   // N1 == N2
constexpr int HID = 768;
constexpr int NH  = 12;
constexpr int HD  = 64;
constexpr int NSPLIT = 2;
constexpr int KSPAN  = N_ / NSPLIT;   // 1024
constexpr int NT     = KSPAN / 64;    // 16 tiles per flash block
constexpr float L2E = 1.4426950408889634f;   // log2(e)

__device__ __forceinline__ short f2bf(float f) {   // RNE float->bf16
    uint32_t u = __builtin_bit_cast(uint32_t, f);
    u = (u + 0x7fffu + ((u >> 16) & 1u)) >> 16;
    return (short)u;
}

// async global->LDS, 16B per lane. LDS dest = wave-uniform base + lane*16.
__device__ __forceinline__ void gload16(const void* g, void* l) {
    __builtin_amdgcn_global_load_lds(
        (const __attribute__((address_space(1))) unsigned int*)g,
        (__attribute__((address_space(3))) unsigned int*)l, 16, 0, 0);
}

// ---------------------------------------------------------------------------
// P0a: X -> (hi|lo) bf16 rows of 1536.  hi = trunc-bf16(x), lo = RNE(x-hi).
// Blocks >= 6144 prescale mask by log2e.
// ---------------------------------------------------------------------------
__global__ __launch_bounds__(256) void prep_x(
    const float* __restrict__ s1, const float* __restrict__ s2,
    const float* __restrict__ mask,
    short* __restrict__ X1, short* __restrict__ X2, float* __restrict__ mks)
{
    const int PT = (B_ * N_ * HID) / 4;       // 786432 quads per tensor
    if (blockIdx.x >= 6144) {
        const int idx = (blockIdx.x - 6144) * 256 + threadIdx.x;   // < 1024
        const float4 mv = *reinterpret_cast<const float4*>(&mask[idx * 4]);
        *reinterpret_cast<float4*>(&mks[idx * 4]) =
            make_float4(mv.x * L2E, mv.y * L2E, mv.z * L2E, mv.w * L2E);
        return;
    }
    int i = blockIdx.x * 256 + threadIdx.x;
    const float* S; short* X;
    if (i < PT) { S = s1; X = X1; } else { S = s2; X = X2; i -= PT; }
    const int e   = i * 4;
    const int row = e / HID;
    const int col = e - row * HID;
    const float4 v = *reinterpret_cast<const float4*>(&S[e]);
    float vs[4] = {v.x, v.y, v.z, v.w};
    short4 hi, lo;
    short* hp = &hi.x; short* lp = &lo.x;
    #pragma unroll
    for (int j = 0; j < 4; ++j) {
        const uint32_t u = __builtin_bit_cast(uint32_t, vs[j]);
        hp[j] = (short)(u >> 16);
        const float hif = __builtin_bit_cast(float, u & 0xffff0000u);
        lp[j] = f2bf(vs[j] - hif);
    }
    short* dst = X + (size_t)row * 1536 + col;
    *reinterpret_cast<short4*>(dst)       = hi;
    *reinterpret_cast<short4*>(dst + 768) = lo;
}

// ---------------------------------------------------------------------------
// P0b: W [k][n] fp32 -> WT [n][k] bf16 (3 matrices).  grid (12,12,3) x 256.
// ---------------------------------------------------------------------------
__global__ __launch_bounds__(256) void prep_w(
    const float* __restrict__ Wq, const float* __restrict__ Wk,
    const float* __restrict__ Wv, short* __restrict__ WT)
{
    const int z = blockIdx.z;
    const float* W = (z == 0) ? Wq : (z == 1) ? Wk : Wv;
    short* O = WT + (size_t)z * HID * HID;
    __shared__ short Tl[64][66];
    const int k0 = blockIdx.x * 64, n0 = blockIdx.y * 64;
    const int t = threadIdx.x;
    const int rr = t >> 4, cc = (t & 15) * 4;
    #pragma unroll
    for (int i = 0; i < 4; ++i) {
        const int row = i * 16 + rr;
        const float4 w = *reinterpret_cast<const float4*>(&W[(size_t)(k0 + row) * HID + n0 + cc]);
        Tl[cc + 0][row] = f2bf(w.x);
        Tl[cc + 1][row] = f2bf(w.y);
        Tl[cc + 2][row] = f2bf(w.z);
        Tl[cc + 3][row] = f2bf(w.w);
    }
    __syncthreads();
    #pragma unroll
    for (int i = 0; i < 4; ++i) {
        const int n = i * 16 + rr;
        short4 o;
        o.x = Tl[n][cc + 0]; o.y = Tl[n][cc + 1];
        o.z = Tl[n][cc + 2]; o.w = Tl[n][cc + 3];
        *reinterpret_cast<short4*>(&O[(size_t)(n0 + n) * HID + k0 + cc]) = o;
    }
}

// ---------------------------------------------------------------------------
// K1: proj GEMM, m97 structure (r16, passing).  grid (32, 6, 3), block 256.
// ---------------------------------------------------------------------------
__global__ __launch_bounds__(256) void proj_mfma(
    const short* __restrict__ X1, const short* __restrict__ X2,
    const short* __restrict__ WT,
    const float* __restrict__ bq, const float* __restrict__ bk,
    const float* __restrict__ bv,
    short* __restrict__ qb, short* __restrict__ kbm, short* __restrict__ vtb)
{
    const int which = blockIdx.z;
    const char* Xb = (const char*)((which == 0) ? X1 : X2);        // row 3072 B
    const char* Wb = (const char*)(WT + (size_t)which * HID * HID); // row 1536 B
    const float* bias = (which == 0) ? bq : (which == 1) ? bk : bv;
    const int m0 = blockIdx.x * 128;
    const int n0 = blockIdx.y * 128;
    const int t = threadIdx.x;
    const int lane = t & 63;
    const int lg = lane >> 4, lm = lane & 15;
    const int wave = __builtin_amdgcn_readfirstlane(t >> 6);
    const int wr = wave >> 1, wc = wave & 1;

    __shared__ __align__(16) char Ls[32768];
    char* Al = Ls;            // 128 rows x 128 B (A tile, swizzled slots)
    char* Bl = Ls + 16384;    // 128 rows x 128 B (B tile)

    const int KSTEPS = (which == 2) ? 12 : 24;

    f32x4 acc[4][4];
    #pragma unroll
    for (int mt = 0; mt < 4; ++mt)
        #pragma unroll
        for (int nt = 0; nt < 4; ++nt) acc[mt][nt] = f32x4{0.f, 0.f, 0.f, 0.f};

    auto stage = [&](int ks) {
        const int ka = ks * 128;            // byte col into X row (hi then lo)
        const int kw = (ks % 12) * 128;     // byte col into WT row (W repeats)
        #pragma unroll
        for (int u = 0; u < 4; ++u) {
            const int c = u * 256 + wave * 64 + lane;   // chunk id 0..1023
            const int row = c >> 3, j = c & 7;
            gload16(Xb + (size_t)(m0 + row) * 3072 + ka + ((j ^ (row & 7)) << 4),
                    Al + u * 4096 + wave * 1024);
        }
        #pragma unroll
        for (int u = 0; u < 4; ++u) {
            const int c = u * 256 + wave * 64 + lane;
            const int row = c >> 3, j = c & 7;
            gload16(Wb + (size_t)(n0 + row) * 1536 + kw + ((j ^ (row & 7)) << 4),
                    Bl + u * 4096 + wave * 1024);
        }
    };

    for (int ks = 0; ks < KSTEPS; ++ks) {
        stage(ks);
        __syncthreads();                    // staged tile visible to all waves
        #pragma unroll
        for (int ksub = 0; ksub < 2; ++ksub) {
            const int jj = ksub * 4 + lg;
            bf16x8 a[4], bb[4];
            #pragma unroll
            for (int mt = 0; mt < 4; ++mt) {
                const int r = wr * 64 + mt * 16 + lm;
                a[mt] = *reinterpret_cast<const bf16x8*>(
                    Al + (r << 7) + ((jj ^ (r & 7)) << 4));
            }
            #pragma unroll
            for (int nt = 0; nt < 4; ++nt) {
                const int r = wc * 64 + nt * 16 + lm;
                bb[nt] = *reinterpret_cast<const bf16x8*>(
                    Bl + (r << 7) + ((jj ^ (r & 7)) << 4));
            }
            __builtin_amdgcn_s_setprio(1);
            #pragma unroll
            for (int mt = 0; mt < 4; ++mt)
                #pragma unroll
                for (int nt = 0; nt < 4; ++nt)
                    acc[mt][nt] = __builtin_amdgcn_mfma_f32_16x16x32_bf16(
                        a[mt], bb[nt], acc[mt][nt], 0, 0, 0);
            __builtin_amdgcn_s_setprio(0);
        }
        __syncthreads();                    // readers done before next stage
    }

    const int b = m0 >> 11;

    if (which != 2) {
        const float sc = (which == 0) ? (0.125f * L2E) : 1.0f;
        short* dst = (which == 0) ? qb : kbm;
        const int head = blockIdx.y * 2 + wc;     // wc*64 selects the head half
        const size_t bh = (size_t)(b * NH + head);
        #pragma unroll
        for (int mt = 0; mt < 4; ++mt)
            #pragma unroll
            for (int nt = 0; nt < 4; ++nt) {
                const int d = nt * 16 + lm;       // 0..63 within head
                const float bi = bias[n0 + wc * 64 + d];
                #pragma unroll
                for (int r = 0; r < 4; ++r) {
                    const int mrow = m0 + wr * 64 + mt * 16 + 4 * lg + r;
                    const int n = mrow & 2047;
                    dst[(bh * N_ + n) * HD + d] = f2bf((acc[mt][nt][r] + bi) * sc);
                }
            }
    } else {
        // transpose via LDS bounce: Ct[128 dd][128 ml] bf16 = 32 KB (all of Ls)
        short* Ct = (short*)Ls;
        #pragma unroll
        for (int mt = 0; mt < 4; ++mt)
            #pragma unroll
            for (int nt = 0; nt < 4; ++nt) {
                const int dd = wc * 64 + nt * 16 + lm;
                const float bi = bias[n0 + dd];
                #pragma unroll
                for (int r = 0; r < 4; ++r) {
                    const int ml = wr * 64 + mt * 16 + 4 * lg + r;
                    Ct[dd * 128 + ml] = f2bf(acc[mt][nt][r] + bi);
                }
            }
        __syncthreads();
        const int dd = t >> 1, seg = t & 1;       // 128 rows x 2 halves
        const int head = (n0 + dd) >> 6;
        const int d = dd & 63;
        const short* src = Ct + dd * 128 + seg * 64;
        short* dv = vtb + ((size_t)(b * NH + head) * HD + d) * N_ + (m0 & 2047) + seg * 64;
        #pragma unroll
        for (int u = 0; u < 8; ++u)
            *reinterpret_cast<int4*>(dv + u * 8) = *reinterpret_cast<const int4*>(src + u * 8);
    }
}

// ---------------------------------------------------------------------------
// K2: split-K flash (r23, passing); K/V staged via gload16, static-zero-max,
// mask in QK C-init, l via deferred ones-B MFMA on packed P.
// grid (N/64, NH, B*NSPLIT), block 256 (4 waves).
// ---------------------------------------------------------------------------
__global__ __launch_bounds__(256) void flash_kernel(
    const short* __restrict__ qb, const short* __restrict__ kbm,
    const short* __restrict__ vtb, const float* __restrict__ mks,
    float* __restrict__ ctx0, float* __restrict__ ctx1,
    float* __restrict__ l_part)
{
    const int qt = blockIdx.x, h = blockIdx.y;
    const int b = blockIdx.z / NSPLIT, s = blockIdx.z % NSPLIT;
    const int t = threadIdx.x;
    const int lane = t & 63;
    const int wave = __builtin_amdgcn_readfirstlane(t >> 6);
    const int lg = lane >> 4, lm = lane & 15;
    const int q0 = qt * 64 + wave * 16;
    const int kstart = s * KSPAN;

    __shared__ __align__(16) char Kl[2][8192];   // 64 K-rows x 128 B, swizzled
    __shared__ __align__(16) char Vl[2][8192];   // 64 V^T-rows x 128 B, swizzled

    const size_t bh = (size_t)(b * NH + h);
    const short* qp  = qb  + (bh * N_ + q0) * HD;
    const char*  kpb = (const char*)(kbm + bh * N_ * HD);   // row 128 B
    const char*  vpb = (const char*)(vtb + bh * HD * N_);   // row N_*2 B
    const float* mk  = mks + (size_t)b * N_;

    const bf16x8 qf0 = *reinterpret_cast<const bf16x8*>(qp + lm * HD + lg * 8);
    const bf16x8 qf1 = *reinterpret_cast<const bf16x8*>(qp + lm * HD + lg * 8 + 32);

    // ones B-frag for the l row-sum MFMA (bf16 1.0 = 0x3F80)
    bf16x4 onesf;
    onesf[0] = (short)0x3F80; onesf[1] = (short)0x3F80;
    onesf[2] = (short)0x3F80; onesf[3] = (short)0x3F80;

    f32x4 cacc[4];
    #pragma unroll
    for (int vt = 0; vt < 4; ++vt) cacc[vt] = f32x4{0.f, 0.f, 0.f, 0.f};
    f32x4 lacc = f32x4{0.f, 0.f, 0.f, 0.f};   // row-sums (same in all cols)
    bf16x4 pa_prev[4];

    auto stageK = [&](int buf, int krow) {
        #pragma unroll
        for (int u = 0; u < 2; ++u) {
            const int c = u * 256 + wave * 64 + lane;   // chunk 0..511
            const int row = c >> 3, j = c & 7;
            gload16(kpb + (size_t)(krow + row) * 128 + ((j ^ (row & 7)) << 4),
                    &Kl[buf][u * 4096 + wave * 1024]);
        }
    };
    auto stageV = [&](int buf, int k0v) {
        #pragma unroll
        for (int u = 0; u < 2; ++u) {
            const int c = u * 256 + wave * 64 + lane;
            const int row = c >> 3, j = c & 7;      // row = V^T d-index
            gload16(vpb + (size_t)row * (N_ * 2) + (size_t)k0v * 2
                        + ((j ^ (row & 7)) << 4),
                    &Vl[buf][u * 4096 + wave * 1024]);
        }
    };

    stageK(0, kstart);
    __syncthreads();

    for (int it = 0; it < NT; ++it) {
        const int k0  = kstart + it * 64;
        const int cur = it & 1;
        const bool more = (it + 1 < NT);

        // stage next K + current V (DMA in flight across this iteration)
        if (more) stageK(cur ^ 1, k0 + 64);
        stageV(cur, k0);

        f32x4 mv4[4];
        #pragma unroll
        for (int kt = 0; kt < 4; ++kt)
            mv4[kt] = *reinterpret_cast<const f32x4*>(&mk[k0 + kt * 16 + 4 * lg]);

        // ---- QK(t) from Kl[cur]; mask folded into C-init ----
        const char* Kb = Kl[cur];
        f32x4 accs[4];
        __builtin_amdgcn_s_setprio(1);
        #pragma unroll
        for (int kt = 0; kt < 4; ++kt) {
            const int r = kt * 16 + lm;
            const bf16x8 kf0 = *reinterpret_cast<const bf16x8*>(
                Kb + (r << 7) + ((lg ^ (r & 7)) << 4));
            const bf16x8 kf1 = *reinterpret_cast<const bf16x8*>(
                Kb + (r << 7) + (((lg + 4) ^ (r & 7)) << 4));
            f32x4 z = mv4[kt];                       // mask as C-input
            z = __builtin_amdgcn_mfma_f32_16x16x32_bf16(kf0, qf0, z, 0, 0, 0);
            z = __builtin_amdgcn_mfma_f32_16x16x32_bf16(kf1, qf1, z, 0, 0, 0);
            accs[kt] = z;
        }
        __builtin_amdgcn_s_setprio(0);

        // ---- deferred: PV(t-1) + l-MFMA(t-1) on pa_prev (hazard-safe) ----
        if (it > 0) {
            const char* Vb = Vl[cur ^ 1];
            __builtin_amdgcn_s_setprio(1);
            #pragma unroll
            for (int kt = 0; kt < 4; ++kt) {
                const int jj = 2 * kt + (lg >> 1);
                #pragma unroll
                for (int vt = 0; vt < 4; ++vt) {
                    const int row = vt * 16 + lm;
                    const bf16x4 vfr = *reinterpret_cast<const bf16x4*>(
                        Vb + (row << 7) + ((jj ^ (row & 7)) << 4) + ((lg & 1) << 3));
                    cacc[vt] = __builtin_amdgcn_mfma_f32_16x16x16bf16_1k(
                        pa_prev[kt], vfr, cacc[vt], 0, 0, 0);
                }
                lacc = __builtin_amdgcn_mfma_f32_16x16x16bf16_1k(
                    pa_prev[kt], onesf, lacc, 0, 0, 0);
            }
            __builtin_amdgcn_s_setprio(0);
        }

        // ---- p = exp2(score), cvt_pk pack (consumed NEXT iteration) ----
        #pragma unroll
        for (int kt = 0; kt < 4; ++kt) {
            const float p0 = exp2f(accs[kt][0]);
            const float p1 = exp2f(accs[kt][1]);
            const float p2 = exp2f(accs[kt][2]);
            const float p3 = exp2f(accs[kt][3]);
            uint32_t u01, u23;
            asm("v_cvt_pk_bf16_f32 %0, %1, %2" : "=v"(u01) : "v"(p0), "v"(p1));
            asm("v_cvt_pk_bf16_f32 %0, %1, %2" : "=v"(u23) : "v"(p2), "v"(p3));
            uint2 u2; u2.x = u01; u2.y = u23;
            pa_prev[kt] = __builtin_bit_cast(bf16x4, u2);
        }

        __syncthreads();   // drains vmcnt: staged K(t+1)/V(t) now visible
    }

    // epilogue: finish the last deferred tile from Vl[(NT-1)&1]
    {
        const char* Vb = Vl[(NT - 1) & 1];
        #pragma unroll
        for (int kt = 0; kt < 4; ++kt) {
            const int jj = 2 * kt + (lg >> 1);
            #pragma unroll
            for (int vt = 0; vt < 4; ++vt) {
                const int row = vt * 16 + lm;
                const bf16x4 vfr = *reinterpret_cast<const bf16x4*>(
                    Vb + (row << 7) + ((jj ^ (row & 7)) << 4) + ((lg & 1) << 3));
                cacc[vt] = __builtin_amdgcn_mfma_f32_16x16x16bf16_1k(
                    pa_prev[kt], vfr, cacc[vt], 0, 0, 0);
            }
            lacc = __builtin_amdgcn_mfma_f32_16x16x16bf16_1k(
                pa_prev[kt], onesf, lacc, 0, 0, 0);
        }
    }

    float* ctxp = (s == 0) ? ctx0 : ctx1;
    #pragma unroll
    for (int r = 0; r < 4; ++r) {
        float* orow = ctxp + ((size_t)b * N_ + q0 + lg * 4 + r) * HID + h * HD;
        #pragma unroll
        for (int vt = 0; vt < 4; ++vt) orow[vt * 16 + lm] = cacc[vt][r];
    }
    // lacc[r] holds l for q-row 4*lg+r (replicated across lm columns)
    if (lm == 0) {
        const size_t idx = (size_t)s * (B_ * NH * N_) + bh * N_ + q0 + lg * 4;
        #pragma unroll
        for (int r = 0; r < 4; ++r) l_part[idx + r] = lacc[r];
    }
}

// ---------------------------------------------------------------------------
// K2b: merge NSPLIT=2 partials.  Static max: L = l0 + l1; stores 1/L.
// grid 12288 x 256.
// ---------------------------------------------------------------------------
__global__ __launch_bounds__(256) void merge_kernel(
    float* __restrict__ ctx0, const float* __restrict__ ctx1,
    const float* __restrict__ l_part, float* __restrict__ l_ws)
{
    const int gid  = blockIdx.x * 256 + threadIdx.x;
    const int row  = gid >> 6;
    const int lane = gid & 63;
    const int bh = row >> 11;
    const int n  = row & 2047;
    const int b  = bh / NH, h = bh % NH;
    constexpr int PS = B_ * NH * N_;

    const float L = l_part[row] + l_part[PS + row];
    const float invL = 1.f / L;

    const size_t cidx = ((size_t)b * N_ + n) * HID + h * HD + lane;
    ctx0[cidx] = (ctx0[cidx] + ctx1[cidx]) * invL;

    if (lane == 0) l_ws[row] = invL;
}

// ---------------------------------------------------------------------------
// K3: attn_weights = sum_h probs / 12.  grid (N/64, N/64, B), block 256.
// [r21 version, passing, ~45us]  K AND Q staged via gload16; static max;
// mask added on the VALU side (exp2(z+mv)) — keeps VGPR low.
// ---------------------------------------------------------------------------
__global__ __launch_bounds__(256) void attnw_kernel(
    const short* __restrict__ qb, const short* __restrict__ kbm,
    const float* __restrict__ mks, const float* __restrict__ l_ws,
    float* __restrict__ out_attn)
{
    const int qt = blockIdx.x, ct = blockIdx.y, b = blockIdx.z;
    const int t = threadIdx.x;
    const int lane = t & 63;
    const int wave = __builtin_amdgcn_readfirstlane(t >> 6);
    const int lg = lane >> 4, lm = lane & 15;
    const int q0 = qt * 64 + wave * 16;
    const int kbase = ct * 64;

    __shared__ __align__(16) char Kl[2][8192];   // 64 K-rows x 128 B, swizzled
    __shared__ __align__(16) char Ql[2][8192];   // 64 Q-rows x 128 B, swizzled

    float mv[4];
    #pragma unroll
    for (int kt = 0; kt < 4; ++kt) mv[kt] = mks[(size_t)b * N_ + kbase + kt * 16 + lm];

    f32x4 accw[4];
    #pragma unroll
    for (int kt = 0; kt < 4; ++kt) accw[kt] = f32x4{0.f, 0.f, 0.f, 0.f};

    auto stageK = [&](int buf, int h) {
        const char* kpb = (const char*)(kbm + ((size_t)(b * NH + h) * N_) * HD);
        #pragma unroll
        for (int u = 0; u < 2; ++u) {
            const int c = u * 256 + wave * 64 + lane;   // chunk 0..511
            const int row = c >> 3, j = c & 7;
            gload16(kpb + (size_t)(kbase + row) * 128 + ((j ^ (row & 7)) << 4),
                    &Kl[buf][u * 4096 + wave * 1024]);
        }
    };
    auto stageQ = [&](int buf, int h) {
        const char* qpb = (const char*)(qb + ((size_t)(b * NH + h) * N_ + qt * 64) * HD);
        #pragma unroll
        for (int u = 0; u < 2; ++u) {
            const int c = u * 256 + wave * 64 + lane;   // chunk 0..511
            const int row = c >> 3, j = c & 7;
            gload16(qpb + (size_t)row * 128 + ((j ^ (row & 7)) << 4),
                    &Ql[buf][u * 4096 + wave * 1024]);
        }
    };

    stageK(0, 0);
    stageQ(0, 0);
    __syncthreads();

    for (int h = 0; h < NH; ++h) {
        const bool more = (h + 1 < NH);
        if (more) {                          // DMA in flight this iteration
            stageK((h + 1) & 1, h + 1);
            stageQ((h + 1) & 1, h + 1);
        }

        const size_t bh = (size_t)(b * NH + h);
        const char* Qb = Ql[h & 1];
        const int rq = wave * 16 + lm;       // q-row within 64-row tile
        const bf16x8 qf0 = *reinterpret_cast<const bf16x8*>(
            Qb + (rq << 7) + ((lg ^ (rq & 7)) << 4));
        const bf16x8 qf1 = *reinterpret_cast<const bf16x8*>(
            Qb + (rq << 7) + (((lg + 4) ^ (rq & 7)) << 4));
        float il[4];
        #pragma unroll
        for (int r = 0; r < 4; ++r)
            il[r] = l_ws[bh * N_ + q0 + lg * 4 + r];    // already 1/L
        const char* Kb = Kl[h & 1];
        __builtin_amdgcn_s_setprio(1);
        #pragma unroll
        for (int kt = 0; kt < 4; ++kt) {
            const int r = kt * 16 + lm;
            const bf16x8 kf0 = *reinterpret_cast<const bf16x8*>(
                Kb + (r << 7) + ((lg ^ (r & 7)) << 4));
            const bf16x8 kf1 = *reinterpret_cast<const bf16x8*>(
                Kb + (r << 7) + (((lg + 4) ^ (r & 7)) << 4));
            f32x4 z = f32x4{0.f, 0.f, 0.f, 0.f};
            z = __builtin_amdgcn_mfma_f32_16x16x32_bf16(qf0, kf0, z, 0, 0, 0);
            z = __builtin_amdgcn_mfma_f32_16x16x32_bf16(qf1, kf1, z, 0, 0, 0);
            #pragma unroll
            for (int rr = 0; rr < 4; ++rr)
                accw[kt][rr] += exp2f(z[rr] + mv[kt]) * il[rr];
        }
        __builtin_amdgcn_s_setprio(0);

        __syncthreads();   // drains vmcnt: staged K/Q(h+1) now visible
    }

    #pragma unroll
    for (int kt = 0; kt < 4; ++kt)
        #pragma unroll
        for (int r = 0; r < 4; ++r)
            out_attn[((size_t)b * N_ + q0 + lg * 4 + r) * N_ + kbase + kt * 16 + lm]
                = accw[kt][r] * (1.0f / 12.0f);
}

// ---------------------------------------------------------------------------
extern "C" void kernel_launch(void* const* d_in, const int* in_sizes, int n_in,
                              void* d_out, int out_size, void* d_ws, size_t ws_size,
                              hipStream_t stream) {
    (void)in_sizes; (void)n_in; (void)out_size;
    const float* s1   = (const float*)d_in[0];
    const float* s2   = (const float*)d_in[1];
    const float* mask = (const float*)d_in[2];
    const float* Wq   = (const float*)d_in[3];
    const float* bq   = (const float*)d_in[4];
    const float* Wk   = (const float*)d_in[5];
    const float* bk   = (const float*)d_in[6];
    const float* Wv   = (const float*)d_in[7];
    const float* bv   = (const float*)d_in[8];

    float* out_ctx  = (float*)d_out;
    float* out_attn = out_ctx + (size_t)B_ * N_ * HID;

    const size_t xlen = (size_t)B_ * N_ * 1536;     // hi|lo shorts per tensor
    const size_t qkv  = (size_t)B_ * NH * N_ * HD;
    const size_t rows = (size_t)B_ * NH * N_;
    short* X1   = (short*)d_ws;
    short* X2   = X1 + xlen;
    short* WT   = X2 + xlen;
    short* qb   = WT + (size_t)3 * HID * HID;
    short* kbm  = qb + qkv;
    short* vtb  = kbm + qkv;
    float* ctx1 = (float*)(vtb + qkv);
    float* l_part = ctx1 + (size_t)B_ * N_ * HID;   // [NSPLIT][rows]
    float* l_ws   = l_part + NSPLIT * rows;
    float* mks    = l_ws + rows;
    const size_t need = (size_t)((char*)(mks + (size_t)B_ * N_) - (char*)d_ws);
    if (ws_size < need) return;

    prep_x<<<6148, 256, 0, stream>>>(s1, s2, mask, X1, X2, mks);
    prep_w<<<dim3(12, 12, 3), 256, 0, stream>>>(Wq, Wk, Wv, WT);
    proj_mfma<<<dim3(32, 6, 3), 256, 0, stream>>>(X1, X2, WT, bq, bk, bv, qb, kbm, vtb);
    flash_kernel<<<dim3(N_ / 64, NH, B_ * NSPLIT), 256, 0, stream>>>(
        qb, kbm, vtb, mks, out_ctx, ctx1, l_part);
    merge_kernel<<<(B_ * N_ * HID) / 256, 256, 0, stream>>>(
        out_ctx, ctx1, l_part, l_ws);
    attnw_kernel<<<dim3(N_ / 64, N_ / 64, B_), 256, 0, stream>>>(
        qb, kbm, mks, l_ws, out_attn);
}

// Round 26
// 144.358 us; speedup vs baseline: 1.0800x; 1.0800x over previous
//
#include <hip/hip_runtime.h>
#include <stdint.h>

// Cross-attention forward: B=2, N1=N2=2048, HID=768, 12 heads x 64.
// Round 26: NSPLIT=1 — flash walks all 32 key-tiles, normalizes ctx
// in-register (l complete per block; lacc replicated across lm -> no
// shuffle) and writes final ctx + l_ws=1/L directly. Deletes the merge
// kernel, one launch gap, and ~38MB HBM (ctx1 + merge RMW). Flash body,
// proj, attnw, prep otherwise byte-identical to r25 (155.9 us, passing).

typedef __attribute__((ext_vector_type(8))) short bf16x8;
typedef __attribute__((ext_vector_type(4))) short bf16x4;
typedef __attribute__((ext_vector_type(4))) float f32x4;

constexpr int B_  = 2;
constexpr int N_  = 2048;   // N1 == N2
constexpr int HID = 768;
constexpr int NH  = 12;
constexpr int HD  = 64;
constexpr int NT  = N_ / 64;   // 32 key-tiles per flash block
constexpr float L2E = 1.4426950408889634f;   // log2(e)

__device__ __forceinline__ short f2bf(float f) {   // RNE float->bf16
    uint32_t u = __builtin_bit_cast(uint32_t, f);
    u = (u + 0x7fffu + ((u >> 16) & 1u)) >> 16;
    return (short)u;
}

// async global->LDS, 16B per lane. LDS dest = wave-uniform base + lane*16.
__device__ __forceinline__ void gload16(const void* g, void* l) {
    __builtin_amdgcn_global_load_lds(
        (const __attribute__((address_space(1))) unsigned int*)g,
        (__attribute__((address_space(3))) unsigned int*)l, 16, 0, 0);
}

// ---------------------------------------------------------------------------
// P0a: X -> (hi|lo) bf16 rows of 1536.  hi = trunc-bf16(x), lo = RNE(x-hi).
// Blocks >= 6144 prescale mask by log2e.
// ---------------------------------------------------------------------------
__global__ __launch_bounds__(256) void prep_x(
    const float* __restrict__ s1, const float* __restrict__ s2,
    const float* __restrict__ mask,
    short* __restrict__ X1, short* __restrict__ X2, float* __restrict__ mks)
{
    const int PT = (B_ * N_ * HID) / 4;       // 786432 quads per tensor
    if (blockIdx.x >= 6144) {
        const int idx = (blockIdx.x - 6144) * 256 + threadIdx.x;   // < 1024
        const float4 mv = *reinterpret_cast<const float4*>(&mask[idx * 4]);
        *reinterpret_cast<float4*>(&mks[idx * 4]) =
            make_float4(mv.x * L2E, mv.y * L2E, mv.z * L2E, mv.w * L2E);
        return;
    }
    int i = blockIdx.x * 256 + threadIdx.x;
    const float* S; short* X;
    if (i < PT) { S = s1; X = X1; } else { S = s2; X = X2; i -= PT; }
    const int e   = i * 4;
    const int row = e / HID;
    const int col = e - row * HID;
    const float4 v = *reinterpret_cast<const float4*>(&S[e]);
    float vs[4] = {v.x, v.y, v.z, v.w};
    short4 hi, lo;
    short* hp = &hi.x; short* lp = &lo.x;
    #pragma unroll
    for (int j = 0; j < 4; ++j) {
        const uint32_t u = __builtin_bit_cast(uint32_t, vs[j]);
        hp[j] = (short)(u >> 16);
        const float hif = __builtin_bit_cast(float, u & 0xffff0000u);
        lp[j] = f2bf(vs[j] - hif);
    }
    short* dst = X + (size_t)row * 1536 + col;
    *reinterpret_cast<short4*>(dst)       = hi;
    *reinterpret_cast<short4*>(dst + 768) = lo;
}

// ---------------------------------------------------------------------------
// P0b: W [k][n] fp32 -> WT [n][k] bf16 (3 matrices).  grid (12,12,3) x 256.
// ---------------------------------------------------------------------------
__global__ __launch_bounds__(256) void prep_w(
    const float* __restrict__ Wq, const float* __restrict__ Wk,
    const float* __restrict__ Wv, short* __restrict__ WT)
{
    const int z = blockIdx.z;
    const float* W = (z == 0) ? Wq : (z == 1) ? Wk : Wv;
    short* O = WT + (size_t)z * HID * HID;
    __shared__ short Tl[64][66];
    const int k0 = blockIdx.x * 64, n0 = blockIdx.y * 64;
    const int t = threadIdx.x;
    const int rr = t >> 4, cc = (t & 15) * 4;
    #pragma unroll
    for (int i = 0; i < 4; ++i) {
        const int row = i * 16 + rr;
        const float4 w = *reinterpret_cast<const float4*>(&W[(size_t)(k0 + row) * HID + n0 + cc]);
        Tl[cc + 0][row] = f2bf(w.x);
        Tl[cc + 1][row] = f2bf(w.y);
        Tl[cc + 2][row] = f2bf(w.z);
        Tl[cc + 3][row] = f2bf(w.w);
    }
    __syncthreads();
    #pragma unroll
    for (int i = 0; i < 4; ++i) {
        const int n = i * 16 + rr;
        short4 o;
        o.x = Tl[n][cc + 0]; o.y = Tl[n][cc + 1];
        o.z = Tl[n][cc + 2]; o.w = Tl[n][cc + 3];
        *reinterpret_cast<short4*>(&O[(size_t)(n0 + n) * HID + k0 + cc]) = o;
    }
}

// ---------------------------------------------------------------------------
// K1: proj GEMM, m97 structure (r16, passing).  grid (32, 6, 3), block 256.
// ---------------------------------------------------------------------------
__global__ __launch_bounds__(256) void proj_mfma(
    const short* __restrict__ X1, const short* __restrict__ X2,
    const short* __restrict__ WT,
    const float* __restrict__ bq, const float* __restrict__ bk,
    const float* __restrict__ bv,
    short* __restrict__ qb, short* __restrict__ kbm, short* __restrict__ vtb)
{
    const int which = blockIdx.z;
    const char* Xb = (const char*)((which == 0) ? X1 : X2);        // row 3072 B
    const char* Wb = (const char*)(WT + (size_t)which * HID * HID); // row 1536 B
    const float* bias = (which == 0) ? bq : (which == 1) ? bk : bv;
    const int m0 = blockIdx.x * 128;
    const int n0 = blockIdx.y * 128;
    const int t = threadIdx.x;
    const int lane = t & 63;
    const int lg = lane >> 4, lm = lane & 15;
    const int wave = __builtin_amdgcn_readfirstlane(t >> 6);
    const int wr = wave >> 1, wc = wave & 1;

    __shared__ __align__(16) char Ls[32768];
    char* Al = Ls;            // 128 rows x 128 B (A tile, swizzled slots)
    char* Bl = Ls + 16384;    // 128 rows x 128 B (B tile)

    const int KSTEPS = (which == 2) ? 12 : 24;

    f32x4 acc[4][4];
    #pragma unroll
    for (int mt = 0; mt < 4; ++mt)
        #pragma unroll
        for (int nt = 0; nt < 4; ++nt) acc[mt][nt] = f32x4{0.f, 0.f, 0.f, 0.f};

    auto stage = [&](int ks) {
        const int ka = ks * 128;            // byte col into X row (hi then lo)
        const int kw = (ks % 12) * 128;     // byte col into WT row (W repeats)
        #pragma unroll
        for (int u = 0; u < 4; ++u) {
            const int c = u * 256 + wave * 64 + lane;   // chunk id 0..1023
            const int row = c >> 3, j = c & 7;
            gload16(Xb + (size_t)(m0 + row) * 3072 + ka + ((j ^ (row & 7)) << 4),
                    Al + u * 4096 + wave * 1024);
        }
        #pragma unroll
        for (int u = 0; u < 4; ++u) {
            const int c = u * 256 + wave * 64 + lane;
            const int row = c >> 3, j = c & 7;
            gload16(Wb + (size_t)(n0 + row) * 1536 + kw + ((j ^ (row & 7)) << 4),
                    Bl + u * 4096 + wave * 1024);
        }
    };

    for (int ks = 0; ks < KSTEPS; ++ks) {
        stage(ks);
        __syncthreads();                    // staged tile visible to all waves
        #pragma unroll
        for (int ksub = 0; ksub < 2; ++ksub) {
            const int jj = ksub * 4 + lg;
            bf16x8 a[4], bb[4];
            #pragma unroll
            for (int mt = 0; mt < 4; ++mt) {
                const int r = wr * 64 + mt * 16 + lm;
                a[mt] = *reinterpret_cast<const bf16x8*>(
                    Al + (r << 7) + ((jj ^ (r & 7)) << 4));
            }
            #pragma unroll
            for (int nt = 0; nt < 4; ++nt) {
                const int r = wc * 64 + nt * 16 + lm;
                bb[nt] = *reinterpret_cast<const bf16x8*>(
                    Bl + (r << 7) + ((jj ^ (r & 7)) << 4));
            }
            __builtin_amdgcn_s_setprio(1);
            #pragma unroll
            for (int mt = 0; mt < 4; ++mt)
                #pragma unroll
                for (int nt = 0; nt < 4; ++nt)
                    acc[mt][nt] = __builtin_amdgcn_mfma_f32_16x16x32_bf16(
                        a[mt], bb[nt], acc[mt][nt], 0, 0, 0);
            __builtin_amdgcn_s_setprio(0);
        }
        __syncthreads();                    // readers done before next stage
    }

    const int b = m0 >> 11;

    if (which != 2) {
        const float sc = (which == 0) ? (0.125f * L2E) : 1.0f;
        short* dst = (which == 0) ? qb : kbm;
        const int head = blockIdx.y * 2 + wc;     // wc*64 selects the head half
        const size_t bh = (size_t)(b * NH + head);
        #pragma unroll
        for (int mt = 0; mt < 4; ++mt)
            #pragma unroll
            for (int nt = 0; nt < 4; ++nt) {
                const int d = nt * 16 + lm;       // 0..63 within head
                const float bi = bias[n0 + wc * 64 + d];
                #pragma unroll
                for (int r = 0; r < 4; ++r) {
                    const int mrow = m0 + wr * 64 + mt * 16 + 4 * lg + r;
                    const int n = mrow & 2047;
                    dst[(bh * N_ + n) * HD + d] = f2bf((acc[mt][nt][r] + bi) * sc);
                }
            }
    } else {
        // transpose via LDS bounce: Ct[128 dd][128 ml] bf16 = 32 KB (all of Ls)
        short* Ct = (short*)Ls;
        #pragma unroll
        for (int mt = 0; mt < 4; ++mt)
            #pragma unroll
            for (int nt = 0; nt < 4; ++nt) {
                const int dd = wc * 64 + nt * 16 + lm;
                const float bi = bias[n0 + dd];
                #pragma unroll
                for (int r = 0; r < 4; ++r) {
                    const int ml = wr * 64 + mt * 16 + 4 * lg + r;
                    Ct[dd * 128 + ml] = f2bf(acc[mt][nt][r] + bi);
                }
            }
        __syncthreads();
        const int dd = t >> 1, seg = t & 1;       // 128 rows x 2 halves
        const int head = (n0 + dd) >> 6;
        const int d = dd & 63;
        const short* src = Ct + dd * 128 + seg * 64;
        short* dv = vtb + ((size_t)(b * NH + head) * HD + d) * N_ + (m0 & 2047) + seg * 64;
        #pragma unroll
        for (int u = 0; u < 8; ++u)
            *reinterpret_cast<int4*>(dv + u * 8) = *reinterpret_cast<const int4*>(src + u * 8);
    }
}

// ---------------------------------------------------------------------------
// K2: flash (full key range per block); K/V staged via gload16, static-zero-
// max, mask in QK C-init, l via deferred ones-B MFMA on packed P.  Epilogue
// normalizes ctx in-register (lacc replicated across lm) and writes l_ws=1/L.
// grid (N/64, NH, B), block 256 (4 waves).
// ---------------------------------------------------------------------------
__global__ __launch_bounds__(256) void flash_kernel(
    const short* __restrict__ qb, const short* __restrict__ kbm,
    const short* __restrict__ vtb, const float* __restrict__ mks,
    float* __restrict__ out_ctx, float* __restrict__ l_ws)
{
    const int qt = blockIdx.x, h = blockIdx.y, b = blockIdx.z;
    const int t = threadIdx.x;
    const int lane = t & 63;
    const int wave = __builtin_amdgcn_readfirstlane(t >> 6);
    const int lg = lane >> 4, lm = lane & 15;
    const int q0 = qt * 64 + wave * 16;

    __shared__ __align__(16) char Kl[2][8192];   // 64 K-rows x 128 B, swizzled
    __shared__ __align__(16) char Vl[2][8192];   // 64 V^T-rows x 128 B, swizzled

    const size_t bh = (size_t)(b * NH + h);
    const short* qp  = qb  + (bh * N_ + q0) * HD;
    const char*  kpb = (const char*)(kbm + bh * N_ * HD);   // row 128 B
    const char*  vpb = (const char*)(vtb + bh * HD * N_);   // row N_*2 B
    const float* mk  = mks + (size_t)b * N_;

    const bf16x8 qf0 = *reinterpret_cast<const bf16x8*>(qp + lm * HD + lg * 8);
    const bf16x8 qf1 = *reinterpret_cast<const bf16x8*>(qp + lm * HD + lg * 8 + 32);

    // ones B-frag for the l row-sum MFMA (bf16 1.0 = 0x3F80)
    bf16x4 onesf;
    onesf[0] = (short)0x3F80; onesf[1] = (short)0x3F80;
    onesf[2] = (short)0x3F80; onesf[3] = (short)0x3F80;

    f32x4 cacc[4];
    #pragma unroll
    for (int vt = 0; vt < 4; ++vt) cacc[vt] = f32x4{0.f, 0.f, 0.f, 0.f};
    f32x4 lacc = f32x4{0.f, 0.f, 0.f, 0.f};   // row-sums (same in all cols)
    bf16x4 pa_prev[4];

    auto stageK = [&](int buf, int krow) {
        #pragma unroll
        for (int u = 0; u < 2; ++u) {
            const int c = u * 256 + wave * 64 + lane;   // chunk 0..511
            const int row = c >> 3, j = c & 7;
            gload16(kpb + (size_t)(krow + row) * 128 + ((j ^ (row & 7)) << 4),
                    &Kl[buf][u * 4096 + wave * 1024]);
        }
    };
    auto stageV = [&](int buf, int k0v) {
        #pragma unroll
        for (int u = 0; u < 2; ++u) {
            const int c = u * 256 + wave * 64 + lane;
            const int row = c >> 3, j = c & 7;      // row = V^T d-index
            gload16(vpb + (size_t)row * (N_ * 2) + (size_t)k0v * 2
                        + ((j ^ (row & 7)) << 4),
                    &Vl[buf][u * 4096 + wave * 1024]);
        }
    };

    stageK(0, 0);
    __syncthreads();

    for (int it = 0; it < NT; ++it) {
        const int k0  = it * 64;
        const int cur = it & 1;
        const bool more = (it + 1 < NT);

        // stage next K + current V (DMA in flight across this iteration)
        if (more) stageK(cur ^ 1, k0 + 64);
        stageV(cur, k0);

        f32x4 mv4[4];
        #pragma unroll
        for (int kt = 0; kt < 4; ++kt)
            mv4[kt] = *reinterpret_cast<const f32x4*>(&mk[k0 + kt * 16 + 4 * lg]);

        // ---- QK(t) from Kl[cur]; mask folded into C-init ----
        const char* Kb = Kl[cur];
        f32x4 accs[4];
        __builtin_amdgcn_s_setprio(1);
        #pragma unroll
        for (int kt = 0; kt < 4; ++kt) {
            const int r = kt * 16 + lm;
            const bf16x8 kf0 = *reinterpret_cast<const bf16x8*>(
                Kb + (r << 7) + ((lg ^ (r & 7)) << 4));
            const bf16x8 kf1 = *reinterpret_cast<const bf16x8*>(
                Kb + (r << 7) + (((lg + 4) ^ (r & 7)) << 4));
            f32x4 z = mv4[kt];                       // mask as C-input
            z = __builtin_amdgcn_mfma_f32_16x16x32_bf16(kf0, qf0, z, 0, 0, 0);
            z = __builtin_amdgcn_mfma_f32_16x16x32_bf16(kf1, qf1, z, 0, 0, 0);
            accs[kt] = z;
        }
        __builtin_amdgcn_s_setprio(0);

        // ---- deferred: PV(t-1) + l-MFMA(t-1) on pa_prev (hazard-safe) ----
        if (it > 0) {
            const char* Vb = Vl[cur ^ 1];
            __builtin_amdgcn_s_setprio(1);
            #pragma unroll
            for (int kt = 0; kt < 4; ++kt) {
                const int jj = 2 * kt + (lg >> 1);
                #pragma unroll
                for (int vt = 0; vt < 4; ++vt) {
                    const int row = vt * 16 + lm;
                    const bf16x4 vfr = *reinterpret_cast<const bf16x4*>(
                        Vb + (row << 7) + ((jj ^ (row & 7)) << 4) + ((lg & 1) << 3));
                    cacc[vt] = __builtin_amdgcn_mfma_f32_16x16x16bf16_1k(
                        pa_prev[kt], vfr, cacc[vt], 0, 0, 0);
                }
                lacc = __builtin_amdgcn_mfma_f32_16x16x16bf16_1k(
                    pa_prev[kt], onesf, lacc, 0, 0, 0);
            }
            __builtin_amdgcn_s_setprio(0);
        }

        // ---- p = exp2(score), cvt_pk pack (consumed NEXT iteration) ----
        #pragma unroll
        for (int kt = 0; kt < 4; ++kt) {
            const float p0 = exp2f(accs[kt][0]);
            const float p1 = exp2f(accs[kt][1]);
            const float p2 = exp2f(accs[kt][2]);
            const float p3 = exp2f(accs[kt][3]);
            uint32_t u01, u23;
            asm("v_cvt_pk_bf16_f32 %0, %1, %2" : "=v"(u01) : "v"(p0), "v"(p1));
            asm("v_cvt_pk_bf16_f32 %0, %1, %2" : "=v"(u23) : "v"(p2), "v"(p3));
            uint2 u2; u2.x = u01; u2.y = u23;
            pa_prev[kt] = __builtin_bit_cast(bf16x4, u2);
        }

        __syncthreads();   // drains vmcnt: staged K(t+1)/V(t) now visible
    }

    // epilogue: finish the last deferred tile from Vl[(NT-1)&1]
    {
        const char* Vb = Vl[(NT - 1) & 1];
        #pragma unroll
        for (int kt = 0; kt < 4; ++kt) {
            const int jj = 2 * kt + (lg >> 1);
            #pragma unroll
            for (int vt = 0; vt < 4; ++vt) {
                const int row = vt * 16 + lm;
                const bf16x4 vfr = *reinterpret_cast<const bf16x4*>(
                    Vb + (row << 7) + ((jj ^ (row & 7)) << 4) + ((lg & 1) << 3));
                cacc[vt] = __builtin_amdgcn_mfma_f32_16x16x16bf16_1k(
                    pa_prev[kt], vfr, cacc[vt], 0, 0, 0);
            }
            lacc = __builtin_amdgcn_mfma_f32_16x16x16bf16_1k(
                pa_prev[kt], onesf, lacc, 0, 0, 0);
        }
    }

    // normalize in-register: lacc[r] = full L for q-row 4*lg+r (all lanes)
    float invl[4];
    #pragma unroll
    for (int r = 0; r < 4; ++r) invl[r] = 1.f / lacc[r];

    #pragma unroll
    for (int r = 0; r < 4; ++r) {
        float* orow = out_ctx + ((size_t)b * N_ + q0 + lg * 4 + r) * HID + h * HD;
        #pragma unroll
        for (int vt = 0; vt < 4; ++vt) orow[vt * 16 + lm] = cacc[vt][r] * invl[r];
    }
    if (lm == 0) {
        const size_t idx = bh * N_ + q0 + lg * 4;
        #pragma unroll
        for (int r = 0; r < 4; ++r) l_ws[idx + r] = invl[r];
    }
}

// ---------------------------------------------------------------------------
// K3: attn_weights = sum_h probs / 12.  grid (N/64, N/64, B), block 256.
// [r21 version, passing]  K AND Q staged via gload16; static max; mask added
// on the VALU side (exp2(z+mv)) — keeps VGPR low.  l_ws holds 1/L.
// ---------------------------------------------------------------------------
__global__ __launch_bounds__(256) void attnw_kernel(
    const short* __restrict__ qb, const short* __restrict__ kbm,
    const float* __restrict__ mks, const float* __restrict__ l_ws,
    float* __restrict__ out_attn)
{
    const int qt = blockIdx.x, ct = blockIdx.y, b = blockIdx.z;
    const int t = threadIdx.x;
    const int lane = t & 63;
    const int wave = __builtin_amdgcn_readfirstlane(t >> 6);
    const int lg = lane >> 4, lm = lane & 15;
    const int q0 = qt * 64 + wave * 16;
    const int kbase = ct * 64;

    __shared__ __align__(16) char Kl[2][8192];   // 64 K-rows x 128 B, swizzled
    __shared__ __align__(16) char Ql[2][8192];   // 64 Q-rows x 128 B, swizzled

    float mv[4];
    #pragma unroll
    for (int kt = 0; kt < 4; ++kt) mv[kt] = mks[(size_t)b * N_ + kbase + kt * 16 + lm];

    f32x4 accw[4];
    #pragma unroll
    for (int kt = 0; kt < 4; ++kt) accw[kt] = f32x4{0.f, 0.f, 0.f, 0.f};

    auto stageK = [&](int buf, int h) {
        const char* kpb = (const char*)(kbm + ((size_t)(b * NH + h) * N_) * HD);
        #pragma unroll
        for (int u = 0; u < 2; ++u) {
            const int c = u * 256 + wave * 64 + lane;   // chunk 0..511
            const int row = c >> 3, j = c & 7;
            gload16(kpb + (size_t)(kbase + row) * 128 + ((j ^ (row & 7)) << 4),
                    &Kl[buf][u * 4096 + wave * 1024]);
        }
    };
    auto stageQ = [&](int buf, int h) {
        const char* qpb = (const char*)(qb + ((size_t)(b * NH + h) * N_ + qt * 64) * HD);
        #pragma unroll
        for (int u = 0; u < 2; ++u) {
            const int c = u * 256 + wave * 64 + lane;   // chunk 0..511
            const int row = c >> 3, j = c & 7;
            gload16(qpb + (size_t)row * 128 + ((j ^ (row & 7)) << 4),
                    &Ql[buf][u * 4096 + wave * 1024]);
        }
    };

    stageK(0, 0);
    stageQ(0, 0);
    __syncthreads();

    for (int h = 0; h < NH; ++h) {
        const bool more = (h + 1 < NH);
        if (more) {                          // DMA in flight this iteration
            stageK((h + 1) & 1, h + 1);
            stageQ((h + 1) & 1, h + 1);
        }

        const size_t bh = (size_t)(b * NH + h);
        const char* Qb = Ql[h & 1];
        const int rq = wave * 16 + lm;       // q-row within 64-row tile
        const bf16x8 qf0 = *reinterpret_cast<const bf16x8*>(
            Qb + (rq << 7) + ((lg ^ (rq & 7)) << 4));
        const bf16x8 qf1 = *reinterpret_cast<const bf16x8*>(
            Qb + (rq << 7) + (((lg + 4) ^ (rq & 7)) << 4));
        float il[4];
        #pragma unroll
        for (int r = 0; r < 4; ++r)
            il[r] = l_ws[bh * N_ + q0 + lg * 4 + r];    // already 1/L
        const char* Kb = Kl[h & 1];
        __builtin_amdgcn_s_setprio(1);
        #pragma unroll
        for (int kt = 0; kt < 4; ++kt) {
            const int r = kt * 16 + lm;
            const bf16x8 kf0 = *reinterpret_cast<const bf16x8*>(
                Kb + (r << 7) + ((lg ^ (r & 7)) << 4));
            const bf16x8 kf1 = *reinterpret_cast<const bf16x8*>(
                Kb + (r << 7) + (((lg + 4) ^ (r & 7)) << 4));
            f32x4 z = f32x4{0.f, 0.f, 0.f, 0.f};
            z = __builtin_amdgcn_mfma_f32_16x16x32_bf16(qf0, kf0, z, 0, 0, 0);
            z = __builtin_amdgcn_mfma_f32_16x16x32_bf16(qf1, kf1, z, 0, 0, 0);
            #pragma unroll
            for (int rr = 0; rr < 4; ++rr)
                accw[kt][rr] += exp2f(z[rr] + mv[kt]) * il[rr];
        }
        __builtin_amdgcn_s_setprio(0);

        __syncthreads();   // drains vmcnt: staged K/Q(h+1) now visible
    }

    #pragma unroll
    for (int kt = 0; kt < 4; ++kt)
        #pragma unroll
        for (int r = 0; r < 4; ++r)
            out_attn[((size_t)b * N_ + q0 + lg * 4 + r) * N_ + kbase + kt * 16 + lm]
                = accw[kt][r] * (1.0f / 12.0f);
}

// ---------------------------------------------------------------------------
extern "C" void kernel_launch(void* const* d_in, const int* in_sizes, int n_in,
                              void* d_out, int out_size, void* d_ws, size_t ws_size,
                              hipStream_t stream) {
    (void)in_sizes; (void)n_in; (void)out_size;
    const float* s1   = (const float*)d_in[0];
    const float* s2   = (const float*)d_in[1];
    const float* mask = (const float*)d_in[2];
    const float* Wq   = (const float*)d_in[3];
    const float* bq   = (const float*)d_in[4];
    const float* Wk   = (const float*)d_in[5];
    const float* bk   = (const float*)d_in[6];
    const float* Wv   = (const float*)d_in[7];
    const float* bv   = (const float*)d_in[8];

    float* out_ctx  = (float*)d_out;
    float* out_attn = out_ctx + (size_t)B_ * N_ * HID;

    const size_t xlen = (size_t)B_ * N_ * 1536;     // hi|lo shorts per tensor
    const size_t qkv  = (size_t)B_ * NH * N_ * HD;
    const size_t rows = (size_t)B_ * NH * N_;
    short* X1   = (short*)d_ws;
    short* X2   = X1 + xlen;
    short* WT   = X2 + xlen;
    short* qb   = WT + (size_t)3 * HID * HID;
    short* kbm  = qb + qkv;
    short* vtb  = kbm + qkv;
    float* l_ws = (float*)(vtb + qkv);
    float* mks  = l_ws + rows;
    const size_t need = (size_t)((char*)(mks + (size_t)B_ * N_) - (char*)d_ws);
    if (ws_size < need) return;

    prep_x<<<6148, 256, 0, stream>>>(s1, s2, mask, X1, X2, mks);
    prep_w<<<dim3(12, 12, 3), 256, 0, stream>>>(Wq, Wk, Wv, WT);
    proj_mfma<<<dim3(32, 6, 3), 256, 0, stream>>>(X1, X2, WT, bq, bk, bv, qb, kbm, vtb);
    flash_kernel<<<dim3(N_ / 64, NH, B_), 256, 0, stream>>>(
        qb, kbm, vtb, mks, out_ctx, l_ws);
    attnw_kernel<<<dim3(N_ / 64, N_ / 64, B_), 256, 0, stream>>>(
        qb, kbm, mks, l_ws, out_attn);
}

// Round 27
// 139.481 us; speedup vs baseline: 1.1178x; 1.0350x over previous
//
#include <hip/hip_runtime.h>
#include <stdint.h>

// Cross-attention forward: B=2, N1=N2=2048, HID=768, 12 heads x 64.
// Round 27: fp16 proj inputs replace the bf16 hi/lo split. fp16's 11-bit
// mantissa puts proj-path error at ~3e-4 (r8's bf16 measurement / 8) vs
// the 4.88e-4 attention floor -> total ~6-8e-4 < 1.416e-3 threshold.
// KSTEPS 24->12 uniformly (proj work halved), prep_x write traffic halved.
// q/k/v outputs stay bf16; flash/attnw/epilogues byte-identical to r26.

typedef __attribute__((ext_vector_type(8))) short bf16x8;
typedef __attribute__((ext_vector_type(4))) short bf16x4;
typedef __attribute__((ext_vector_type(8))) _Float16 f16x8;
typedef __attribute__((ext_vector_type(4))) float f32x4;

constexpr int B_  = 2;
constexpr int N_  = 2048;   // N1 == N2
constexpr int HID = 768;
constexpr int NH  = 12;
constexpr int HD  = 64;
constexpr int NT  = N_ / 64;   // 32 key-tiles per flash block
constexpr float L2E = 1.4426950408889634f;   // log2(e)

__device__ __forceinline__ short f2bf(float f) {   // RNE float->bf16
    uint32_t u = __builtin_bit_cast(uint32_t, f);
    u = (u + 0x7fffu + ((u >> 16) & 1u)) >> 16;
    return (short)u;
}

__device__ __forceinline__ short f2h(float f) {    // RNE float->fp16
    _Float16 h = (_Float16)f;
    return __builtin_bit_cast(short, h);
}

// async global->LDS, 16B per lane. LDS dest = wave-uniform base + lane*16.
__device__ __forceinline__ void gload16(const void* g, void* l) {
    __builtin_amdgcn_global_load_lds(
        (const __attribute__((address_space(1))) unsigned int*)g,
        (__attribute__((address_space(3))) unsigned int*)l, 16, 0, 0);
}

// ---------------------------------------------------------------------------
// P0a: X -> fp16 rows of 768.  Blocks >= 6144 prescale mask by log2e.
// ---------------------------------------------------------------------------
__global__ __launch_bounds__(256) void prep_x(
    const float* __restrict__ s1, const float* __restrict__ s2,
    const float* __restrict__ mask,
    short* __restrict__ X1, short* __restrict__ X2, float* __restrict__ mks)
{
    const int PT = (B_ * N_ * HID) / 4;       // 786432 quads per tensor
    if (blockIdx.x >= 6144) {
        const int idx = (blockIdx.x - 6144) * 256 + threadIdx.x;   // < 1024
        const float4 mv = *reinterpret_cast<const float4*>(&mask[idx * 4]);
        *reinterpret_cast<float4*>(&mks[idx * 4]) =
            make_float4(mv.x * L2E, mv.y * L2E, mv.z * L2E, mv.w * L2E);
        return;
    }
    int i = blockIdx.x * 256 + threadIdx.x;
    const float* S; short* X;
    if (i < PT) { S = s1; X = X1; } else { S = s2; X = X2; i -= PT; }
    const int e = i * 4;
    const float4 v = *reinterpret_cast<const float4*>(&S[e]);
    short4 hv;
    hv.x = f2h(v.x); hv.y = f2h(v.y); hv.z = f2h(v.z); hv.w = f2h(v.w);
    *reinterpret_cast<short4*>(&X[e]) = hv;
}

// ---------------------------------------------------------------------------
// P0b: W [k][n] fp32 -> WT [n][k] fp16 (3 matrices).  grid (12,12,3) x 256.
// ---------------------------------------------------------------------------
__global__ __launch_bounds__(256) void prep_w(
    const float* __restrict__ Wq, const float* __restrict__ Wk,
    const float* __restrict__ Wv, short* __restrict__ WT)
{
    const int z = blockIdx.z;
    const float* W = (z == 0) ? Wq : (z == 1) ? Wk : Wv;
    short* O = WT + (size_t)z * HID * HID;
    __shared__ short Tl[64][66];
    const int k0 = blockIdx.x * 64, n0 = blockIdx.y * 64;
    const int t = threadIdx.x;
    const int rr = t >> 4, cc = (t & 15) * 4;
    #pragma unroll
    for (int i = 0; i < 4; ++i) {
        const int row = i * 16 + rr;
        const float4 w = *reinterpret_cast<const float4*>(&W[(size_t)(k0 + row) * HID + n0 + cc]);
        Tl[cc + 0][row] = f2h(w.x);
        Tl[cc + 1][row] = f2h(w.y);
        Tl[cc + 2][row] = f2h(w.z);
        Tl[cc + 3][row] = f2h(w.w);
    }
    __syncthreads();
    #pragma unroll
    for (int i = 0; i < 4; ++i) {
        const int n = i * 16 + rr;
        short4 o;
        o.x = Tl[n][cc + 0]; o.y = Tl[n][cc + 1];
        o.z = Tl[n][cc + 2]; o.w = Tl[n][cc + 3];
        *reinterpret_cast<short4*>(&O[(size_t)(n0 + n) * HID + k0 + cc]) = o;
    }
}

// ---------------------------------------------------------------------------
// K1: proj GEMM, m97 structure, fp16 inputs (KSTEPS=12 for q,k,v).
// grid (32, 6, 3), block 256 (4 waves 2x2).  Outputs bf16 q/k/v (unchanged).
// ---------------------------------------------------------------------------
__global__ __launch_bounds__(256) void proj_mfma(
    const short* __restrict__ X1, const short* __restrict__ X2,
    const short* __restrict__ WT,
    const float* __restrict__ bq, const float* __restrict__ bk,
    const float* __restrict__ bv,
    short* __restrict__ qb, short* __restrict__ kbm, short* __restrict__ vtb)
{
    const int which = blockIdx.z;
    const char* Xb = (const char*)((which == 0) ? X1 : X2);        // row 1536 B
    const char* Wb = (const char*)(WT + (size_t)which * HID * HID); // row 1536 B
    const float* bias = (which == 0) ? bq : (which == 1) ? bk : bv;
    const int m0 = blockIdx.x * 128;
    const int n0 = blockIdx.y * 128;
    const int t = threadIdx.x;
    const int lane = t & 63;
    const int lg = lane >> 4, lm = lane & 15;
    const int wave = __builtin_amdgcn_readfirstlane(t >> 6);
    const int wr = wave >> 1, wc = wave & 1;

    __shared__ __align__(16) char Ls[32768];
    char* Al = Ls;            // 128 rows x 128 B (A tile, swizzled slots)
    char* Bl = Ls + 16384;    // 128 rows x 128 B (B tile)

    constexpr int KSTEPS = 12;

    f32x4 acc[4][4];
    #pragma unroll
    for (int mt = 0; mt < 4; ++mt)
        #pragma unroll
        for (int nt = 0; nt < 4; ++nt) acc[mt][nt] = f32x4{0.f, 0.f, 0.f, 0.f};

    auto stage = [&](int ks) {
        const int kb = ks * 128;            // byte col (64 fp16 per K-step)
        #pragma unroll
        for (int u = 0; u < 4; ++u) {
            const int c = u * 256 + wave * 64 + lane;   // chunk id 0..1023
            const int row = c >> 3, j = c & 7;
            gload16(Xb + (size_t)(m0 + row) * 1536 + kb + ((j ^ (row & 7)) << 4),
                    Al + u * 4096 + wave * 1024);
        }
        #pragma unroll
        for (int u = 0; u < 4; ++u) {
            const int c = u * 256 + wave * 64 + lane;
            const int row = c >> 3, j = c & 7;
            gload16(Wb + (size_t)(n0 + row) * 1536 + kb + ((j ^ (row & 7)) << 4),
                    Bl + u * 4096 + wave * 1024);
        }
    };

    for (int ks = 0; ks < KSTEPS; ++ks) {
        stage(ks);
        __syncthreads();                    // staged tile visible to all waves
        #pragma unroll
        for (int ksub = 0; ksub < 2; ++ksub) {
            const int jj = ksub * 4 + lg;
            f16x8 a[4], bb[4];
            #pragma unroll
            for (int mt = 0; mt < 4; ++mt) {
                const int r = wr * 64 + mt * 16 + lm;
                a[mt] = *reinterpret_cast<const f16x8*>(
                    Al + (r << 7) + ((jj ^ (r & 7)) << 4));
            }
            #pragma unroll
            for (int nt = 0; nt < 4; ++nt) {
                const int r = wc * 64 + nt * 16 + lm;
                bb[nt] = *reinterpret_cast<const f16x8*>(
                    Bl + (r << 7) + ((jj ^ (r & 7)) << 4));
            }
            __builtin_amdgcn_s_setprio(1);
            #pragma unroll
            for (int mt = 0; mt < 4; ++mt)
                #pragma unroll
                for (int nt = 0; nt < 4; ++nt)
                    acc[mt][nt] = __builtin_amdgcn_mfma_f32_16x16x32_f16(
                        a[mt], bb[nt], acc[mt][nt], 0, 0, 0);
            __builtin_amdgcn_s_setprio(0);
        }
        __syncthreads();                    // readers done before next stage
    }

    const int b = m0 >> 11;

    if (which != 2) {
        const float sc = (which == 0) ? (0.125f * L2E) : 1.0f;
        short* dst = (which == 0) ? qb : kbm;
        const int head = blockIdx.y * 2 + wc;     // wc*64 selects the head half
        const size_t bh = (size_t)(b * NH + head);
        #pragma unroll
        for (int mt = 0; mt < 4; ++mt)
            #pragma unroll
            for (int nt = 0; nt < 4; ++nt) {
                const int d = nt * 16 + lm;       // 0..63 within head
                const float bi = bias[n0 + wc * 64 + d];
                #pragma unroll
                for (int r = 0; r < 4; ++r) {
                    const int mrow = m0 + wr * 64 + mt * 16 + 4 * lg + r;
                    const int n = mrow & 2047;
                    dst[(bh * N_ + n) * HD + d] = f2bf((acc[mt][nt][r] + bi) * sc);
                }
            }
    } else {
        // transpose via LDS bounce: Ct[128 dd][128 ml] bf16 = 32 KB (all of Ls)
        short* Ct = (short*)Ls;
        #pragma unroll
        for (int mt = 0; mt < 4; ++mt)
            #pragma unroll
            for (int nt = 0; nt < 4; ++nt) {
                const int dd = wc * 64 + nt * 16 + lm;
                const float bi = bias[n0 + dd];
                #pragma unroll
                for (int r = 0; r < 4; ++r) {
                    const int ml = wr * 64 + mt * 16 + 4 * lg + r;
                    Ct[dd * 128 + ml] = f2bf(acc[mt][nt][r] + bi);
                }
            }
        __syncthreads();
        const int dd = t >> 1, seg = t & 1;       // 128 rows x 2 halves
        const int head = (n0 + dd) >> 6;
        const int d = dd & 63;
        const short* src = Ct + dd * 128 + seg * 64;
        short* dv = vtb + ((size_t)(b * NH + head) * HD + d) * N_ + (m0 & 2047) + seg * 64;
        #pragma unroll
        for (int u = 0; u < 8; ++u)
            *reinterpret_cast<int4*>(dv + u * 8) = *reinterpret_cast<const int4*>(src + u * 8);
    }
}

// ---------------------------------------------------------------------------
// K2: flash (full key range per block); K/V staged via gload16, static-zero-
// max, mask in QK C-init, l via deferred ones-B MFMA on packed P.  Epilogue
// normalizes ctx in-register and writes l_ws=1/L.  [r26, passing]
// grid (N/64, NH, B), block 256 (4 waves).
// ---------------------------------------------------------------------------
__global__ __launch_bounds__(256) void flash_kernel(
    const short* __restrict__ qb, const short* __restrict__ kbm,
    const short* __restrict__ vtb, const float* __restrict__ mks,
    float* __restrict__ out_ctx, float* __restrict__ l_ws)
{
    const int qt = blockIdx.x, h = blockIdx.y, b = blockIdx.z;
    const int t = threadIdx.x;
    const int lane = t & 63;
    const int wave = __builtin_amdgcn_readfirstlane(t >> 6);
    const int lg = lane >> 4, lm = lane & 15;
    const int q0 = qt * 64 + wave * 16;

    __shared__ __align__(16) char Kl[2][8192];   // 64 K-rows x 128 B, swizzled
    __shared__ __align__(16) char Vl[2][8192];   // 64 V^T-rows x 128 B, swizzled

    const size_t bh = (size_t)(b * NH + h);
    const short* qp  = qb  + (bh * N_ + q0) * HD;
    const char*  kpb = (const char*)(kbm + bh * N_ * HD);   // row 128 B
    const char*  vpb = (const char*)(vtb + bh * HD * N_);   // row N_*2 B
    const float* mk  = mks + (size_t)b * N_;

    const bf16x8 qf0 = *reinterpret_cast<const bf16x8*>(qp + lm * HD + lg * 8);
    const bf16x8 qf1 = *reinterpret_cast<const bf16x8*>(qp + lm * HD + lg * 8 + 32);

    // ones B-frag for the l row-sum MFMA (bf16 1.0 = 0x3F80)
    bf16x4 onesf;
    onesf[0] = (short)0x3F80; onesf[1] = (short)0x3F80;
    onesf[2] = (short)0x3F80; onesf[3] = (short)0x3F80;

    f32x4 cacc[4];
    #pragma unroll
    for (int vt = 0; vt < 4; ++vt) cacc[vt] = f32x4{0.f, 0.f, 0.f, 0.f};
    f32x4 lacc = f32x4{0.f, 0.f, 0.f, 0.f};   // row-sums (same in all cols)
    bf16x4 pa_prev[4];

    auto stageK = [&](int buf, int krow) {
        #pragma unroll
        for (int u = 0; u < 2; ++u) {
            const int c = u * 256 + wave * 64 + lane;   // chunk 0..511
            const int row = c >> 3, j = c & 7;
            gload16(kpb + (size_t)(krow + row) * 128 + ((j ^ (row & 7)) << 4),
                    &Kl[buf][u * 4096 + wave * 1024]);
        }
    };
    auto stageV = [&](int buf, int k0v) {
        #pragma unroll
        for (int u = 0; u < 2; ++u) {
            const int c = u * 256 + wave * 64 + lane;
            const int row = c >> 3, j = c & 7;      // row = V^T d-index
            gload16(vpb + (size_t)row * (N_ * 2) + (size_t)k0v * 2
                        + ((j ^ (row & 7)) << 4),
                    &Vl[buf][u * 4096 + wave * 1024]);
        }
    };

    stageK(0, 0);
    __syncthreads();

    for (int it = 0; it < NT; ++it) {
        const int k0  = it * 64;
        const int cur = it & 1;
        const bool more = (it + 1 < NT);

        // stage next K + current V (DMA in flight across this iteration)
        if (more) stageK(cur ^ 1, k0 + 64);
        stageV(cur, k0);

        f32x4 mv4[4];
        #pragma unroll
        for (int kt = 0; kt < 4; ++kt)
            mv4[kt] = *reinterpret_cast<const f32x4*>(&mk[k0 + kt * 16 + 4 * lg]);

        // ---- QK(t) from Kl[cur]; mask folded into C-init ----
        const char* Kb = Kl[cur];
        f32x4 accs[4];
        __builtin_amdgcn_s_setprio(1);
        #pragma unroll
        for (int kt = 0; kt < 4; ++kt) {
            const int r = kt * 16 + lm;
            const bf16x8 kf0 = *reinterpret_cast<const bf16x8*>(
                Kb + (r << 7) + ((lg ^ (r & 7)) << 4));
            const bf16x8 kf1 = *reinterpret_cast<const bf16x8*>(
                Kb + (r << 7) + (((lg + 4) ^ (r & 7)) << 4));
            f32x4 z = mv4[kt];                       // mask as C-input
            z = __builtin_amdgcn_mfma_f32_16x16x32_bf16(kf0, qf0, z, 0, 0, 0);
            z = __builtin_amdgcn_mfma_f32_16x16x32_bf16(kf1, qf1, z, 0, 0, 0);
            accs[kt] = z;
        }
        __builtin_amdgcn_s_setprio(0);

        // ---- deferred: PV(t-1) + l-MFMA(t-1) on pa_prev (hazard-safe) ----
        if (it > 0) {
            const char* Vb = Vl[cur ^ 1];
            __builtin_amdgcn_s_setprio(1);
            #pragma unroll
            for (int kt = 0; kt < 4; ++kt) {
                const int jj = 2 * kt + (lg >> 1);
                #pragma unroll
                for (int vt = 0; vt < 4; ++vt) {
                    const int row = vt * 16 + lm;
                    const bf16x4 vfr = *reinterpret_cast<const bf16x4*>(
                        Vb + (row << 7) + ((jj ^ (row & 7)) << 4) + ((lg & 1) << 3));
                    cacc[vt] = __builtin_amdgcn_mfma_f32_16x16x16bf16_1k(
                        pa_prev[kt], vfr, cacc[vt], 0, 0, 0);
                }
                lacc = __builtin_amdgcn_mfma_f32_16x16x16bf16_1k(
                    pa_prev[kt], onesf, lacc, 0, 0, 0);
            }
            __builtin_amdgcn_s_setprio(0);
        }

        // ---- p = exp2(score), cvt_pk pack (consumed NEXT iteration) ----
        #pragma unroll
        for (int kt = 0; kt < 4; ++kt) {
            const float p0 = exp2f(accs[kt][0]);
            const float p1 = exp2f(accs[kt][1]);
            const float p2 = exp2f(accs[kt][2]);
            const float p3 = exp2f(accs[kt][3]);
            uint32_t u01, u23;
            asm("v_cvt_pk_bf16_f32 %0, %1, %2" : "=v"(u01) : "v"(p0), "v"(p1));
            asm("v_cvt_pk_bf16_f32 %0, %1, %2" : "=v"(u23) : "v"(p2), "v"(p3));
            uint2 u2; u2.x = u01; u2.y = u23;
            pa_prev[kt] = __builtin_bit_cast(bf16x4, u2);
        }

        __syncthreads();   // drains vmcnt: staged K(t+1)/V(t) now visible
    }

    // epilogue: finish the last deferred tile from Vl[(NT-1)&1]
    {
        const char* Vb = Vl[(NT - 1) & 1];
        #pragma unroll
        for (int kt = 0; kt < 4; ++kt) {
            const int jj = 2 * kt + (lg >> 1);
            #pragma unroll
            for (int vt = 0; vt < 4; ++vt) {
                const int row = vt * 16 + lm;
                const bf16x4 vfr = *reinterpret_cast<const bf16x4*>(
                    Vb + (row << 7) + ((jj ^ (row & 7)) << 4) + ((lg & 1) << 3));
                cacc[vt] = __builtin_amdgcn_mfma_f32_16x16x16bf16_1k(
                    pa_prev[kt], vfr, cacc[vt], 0, 0, 0);
            }
            lacc = __builtin_amdgcn_mfma_f32_16x16x16bf16_1k(
                pa_prev[kt], onesf, lacc, 0, 0, 0);
        }
    }

    // normalize in-register: lacc[r] = full L for q-row 4*lg+r (all lanes)
    float invl[4];
    #pragma unroll
    for (int r = 0; r < 4; ++r) invl[r] = 1.f / lacc[r];

    #pragma unroll
    for (int r = 0; r < 4; ++r) {
        float* orow = out_ctx + ((size_t)b * N_ + q0 + lg * 4 + r) * HID + h * HD;
        #pragma unroll
        for (int vt = 0; vt < 4; ++vt) orow[vt * 16 + lm] = cacc[vt][r] * invl[r];
    }
    if (lm == 0) {
        const size_t idx = bh * N_ + q0 + lg * 4;
        #pragma unroll
        for (int r = 0; r < 4; ++r) l_ws[idx + r] = invl[r];
    }
}

// ---------------------------------------------------------------------------
// K3: attn_weights = sum_h probs / 12.  grid (N/64, N/64, B), block 256.
// [r21/r26 version, passing]  K AND Q staged via gload16; static max; mask
// added on the VALU side (exp2(z+mv)).  l_ws holds 1/L.
// ---------------------------------------------------------------------------
__global__ __launch_bounds__(256) void attnw_kernel(
    const short* __restrict__ qb, const short* __restrict__ kbm,
    const float* __restrict__ mks, const float* __restrict__ l_ws,
    float* __restrict__ out_attn)
{
    const int qt = blockIdx.x, ct = blockIdx.y, b = blockIdx.z;
    const int t = threadIdx.x;
    const int lane = t & 63;
    const int wave = __builtin_amdgcn_readfirstlane(t >> 6);
    const int lg = lane >> 4, lm = lane & 15;
    const int q0 = qt * 64 + wave * 16;
    const int kbase = ct * 64;

    __shared__ __align__(16) char Kl[2][8192];   // 64 K-rows x 128 B, swizzled
    __shared__ __align__(16) char Ql[2][8192];   // 64 Q-rows x 128 B, swizzled

    float mv[4];
    #pragma unroll
    for (int kt = 0; kt < 4; ++kt) mv[kt] = mks[(size_t)b * N_ + kbase + kt * 16 + lm];

    f32x4 accw[4];
    #pragma unroll
    for (int kt = 0; kt < 4; ++kt) accw[kt] = f32x4{0.f, 0.f, 0.f, 0.f};

    auto stageK = [&](int buf, int h) {
        const char* kpb = (const char*)(kbm + ((size_t)(b * NH + h) * N_) * HD);
        #pragma unroll
        for (int u = 0; u < 2; ++u) {
            const int c = u * 256 + wave * 64 + lane;   // chunk 0..511
            const int row = c >> 3, j = c & 7;
            gload16(kpb + (size_t)(kbase + row) * 128 + ((j ^ (row & 7)) << 4),
                    &Kl[buf][u * 4096 + wave * 1024]);
        }
    };
    auto stageQ = [&](int buf, int h) {
        const char* qpb = (const char*)(qb + ((size_t)(b * NH + h) * N_ + qt * 64) * HD);
        #pragma unroll
        for (int u = 0; u < 2; ++u) {
            const int c = u * 256 + wave * 64 + lane;   // chunk 0..511
            const int row = c >> 3, j = c & 7;
            gload16(qpb + (size_t)row * 128 + ((j ^ (row & 7)) << 4),
                    &Ql[buf][u * 4096 + wave * 1024]);
        }
    };

    stageK(0, 0);
    stageQ(0, 0);
    __syncthreads();

    for (int h = 0; h < NH; ++h) {
        const bool more = (h + 1 < NH);
        if (more) {                          // DMA in flight this iteration
            stageK((h + 1) & 1, h + 1);
            stageQ((h + 1) & 1, h + 1);
        }

        const size_t bh = (size_t)(b * NH + h);
        const char* Qb = Ql[h & 1];
        const int rq = wave * 16 + lm;       // q-row within 64-row tile
        const bf16x8 qf0 = *reinterpret_cast<const bf16x8*>(
            Qb + (rq << 7) + ((lg ^ (rq & 7)) << 4));
        const bf16x8 qf1 = *reinterpret_cast<const bf16x8*>(
            Qb + (rq << 7) + (((lg + 4) ^ (rq & 7)) << 4));
        float il[4];
        #pragma unroll
        for (int r = 0; r < 4; ++r)
            il[r] = l_ws[bh * N_ + q0 + lg * 4 + r];    // already 1/L
        const char* Kb = Kl[h & 1];
        __builtin_amdgcn_s_setprio(1);
        #pragma unroll
        for (int kt = 0; kt < 4; ++kt) {
            const int r = kt * 16 + lm;
            const bf16x8 kf0 = *reinterpret_cast<const bf16x8*>(
                Kb + (r << 7) + ((lg ^ (r & 7)) << 4));
            const bf16x8 kf1 = *reinterpret_cast<const bf16x8*>(
                Kb + (r << 7) + (((lg + 4) ^ (r & 7)) << 4));
            f32x4 z = f32x4{0.f, 0.f, 0.f, 0.f};
            z = __builtin_amdgcn_mfma_f32_16x16x32_bf16(qf0, kf0, z, 0, 0, 0);
            z = __builtin_amdgcn_mfma_f32_16x16x32_bf16(qf1, kf1, z, 0, 0, 0);
            #pragma unroll
            for (int rr = 0; rr < 4; ++rr)
                accw[kt][rr] += exp2f(z[rr] + mv[kt]) * il[rr];
        }
        __builtin_amdgcn_s_setprio(0);

        __syncthreads();   // drains vmcnt: staged K/Q(h+1) now visible
    }

    #pragma unroll
    for (int kt = 0; kt < 4; ++kt)
        #pragma unroll
        for (int r = 0; r < 4; ++r)
            out_attn[((size_t)b * N_ + q0 + lg * 4 + r) * N_ + kbase + kt * 16 + lm]
                = accw[kt][r] * (1.0f / 12.0f);
}

// ---------------------------------------------------------------------------
extern "C" void kernel_launch(void* const* d_in, const int* in_sizes, int n_in,
                              void* d_out, int out_size, void* d_ws, size_t ws_size,
                              hipStream_t stream) {
    (void)in_sizes; (void)n_in; (void)out_size;
    const float* s1   = (const float*)d_in[0];
    const float* s2   = (const float*)d_in[1];
    const float* mask = (const float*)d_in[2];
    const float* Wq   = (const float*)d_in[3];
    const float* bq   = (const float*)d_in[4];
    const float* Wk   = (const float*)d_in[5];
    const float* bk   = (const float*)d_in[6];
    const float* Wv   = (const float*)d_in[7];
    const float* bv   = (const float*)d_in[8];

    float* out_ctx  = (float*)d_out;
    float* out_attn = out_ctx + (size_t)B_ * N_ * HID;

    const size_t xlen = (size_t)B_ * N_ * HID;      // fp16 shorts per tensor
    const size_t qkv  = (size_t)B_ * NH * N_ * HD;
    const size_t rows = (size_t)B_ * NH * N_;
    short* X1   = (short*)d_ws;
    short* X2   = X1 + xlen;
    short* WT   = X2 + xlen;
    short* qb   = WT + (size_t)3 * HID * HID;
    short* kbm  = qb + qkv;
    short* vtb  = kbm + qkv;
    float* l_ws = (float*)(vtb + qkv);
    float* mks  = l_ws + rows;
    const size_t need = (size_t)((char*)(mks + (size_t)B_ * N_) - (char*)d_ws);
    if (ws_size < need) return;

    prep_x<<<6148, 256, 0, stream>>>(s1, s2, mask, X1, X2, mks);
    prep_w<<<dim3(12, 12, 3), 256, 0, stream>>>(Wq, Wk, Wv, WT);
    proj_mfma<<<dim3(32, 6, 3), 256, 0, stream>>>(X1, X2, WT, bq, bk, bv, qb, kbm, vtb);
    flash_kernel<<<dim3(N_ / 64, NH, B_), 256, 0, stream>>>(
        qb, kbm, vtb, mks, out_ctx, l_ws);
    attnw_kernel<<<dim3(N_ / 64, N_ / 64, B_), 256, 0, stream>>>(
        qb, kbm, mks, l_ws, out_attn);
}